// Round 1
// baseline (264.131 us; speedup 1.0000x reference)
//
#include <hip/hip_runtime.h>

// Elementwise 16-step spike recurrence:
//   v=|x|; z=0; o=0;
//   for t: v -= z*h[t]; z = (v > T[t]); o += z*d[t];
//   out = o * sign(x)
// Note: (v-T)/(|v|+1) > 0  <=>  v > T  (denominator > 0), so the divide is
// eliminated. z in {0,1} makes z*h and z*d exact, so fma contraction cannot
// change results vs the reference's mul+sub -> bit-exact.

__global__ __launch_bounds__(256) void spike_scan_kernel(
    const float* __restrict__ x,
    const float* __restrict__ h,
    const float* __restrict__ d,
    const float* __restrict__ T,
    float* __restrict__ out,
    long long n4, long long n)
{
    // Uniform coefficient loads -> scalar (s_load) path, kept in SGPRs.
    float hh[16], dd[16], TT[16];
#pragma unroll
    for (int t = 0; t < 16; ++t) {
        hh[t] = h[t];
        dd[t] = d[t];
        TT[t] = T[t];
    }

    const long long stride = (long long)gridDim.x * blockDim.x;
    long long i = (long long)blockIdx.x * blockDim.x + threadIdx.x;

    for (; i < n4; i += stride) {
        float4 xv = reinterpret_cast<const float4*>(x)[i];
        float4 r;
        float* xp = &xv.x;
        float* rp = &r.x;
#pragma unroll
        for (int j = 0; j < 4; ++j) {
            const float xj = xp[j];
            float v = fabsf(xj);
            float z = 0.0f;
            float o = 0.0f;
#pragma unroll
            for (int t = 0; t < 16; ++t) {
                v = fmaf(-z, hh[t], v);      // exact: z in {0,1}
                z = (v > TT[t]) ? 1.0f : 0.0f;
                o = fmaf(z, dd[t], o);       // exact product, single add rounding
            }
            o = copysignf(o, xj);
            rp[j] = (xj == 0.0f) ? 0.0f : o; // sign(0) = 0 semantics
        }
        reinterpret_cast<float4*>(out)[i] = r;
    }

    // Scalar tail (n not divisible by 4) — handled by first block.
    const long long tail_start = n4 * 4;
    if (blockIdx.x == 0) {
        for (long long k = tail_start + threadIdx.x; k < n; k += blockDim.x) {
            const float xj = x[k];
            float v = fabsf(xj);
            float z = 0.0f;
            float o = 0.0f;
#pragma unroll
            for (int t = 0; t < 16; ++t) {
                v = fmaf(-z, hh[t], v);
                z = (v > TT[t]) ? 1.0f : 0.0f;
                o = fmaf(z, dd[t], o);
            }
            o = copysignf(o, xj);
            out[k] = (xj == 0.0f) ? 0.0f : o;
        }
    }
}

extern "C" void kernel_launch(void* const* d_in, const int* in_sizes, int n_in,
                              void* d_out, int out_size, void* d_ws, size_t ws_size,
                              hipStream_t stream) {
    const float* x = (const float*)d_in[0];
    const float* h = (const float*)d_in[1];
    const float* d = (const float*)d_in[2];
    const float* T = (const float*)d_in[3];
    float* out = (float*)d_out;

    const long long n = (long long)out_size;
    const long long n4 = n / 4;

    const int block = 256;
    // Memory-bound streaming: ~2048 blocks (8 blocks/CU) + grid-stride.
    int grid = 2048;
    const long long work_items = (n4 + block - 1) / block;
    if (work_items < grid) grid = (int)(work_items > 0 ? work_items : 1);

    spike_scan_kernel<<<grid, block, 0, stream>>>(x, h, d, T, out, n4, n);
}